// Round 3
// baseline (495.515 us; speedup 1.0000x reference)
//
#include <hip/hip_runtime.h>

typedef __attribute__((ext_vector_type(4))) float f32x4;
typedef __attribute__((ext_vector_type(8))) short short8;

#define T_TOK 16384
#define D_DIM 4096
#define E_EXP 64
#define BKC 64
#define NCHUNK (D_DIM / BKC)     // 64
#define GAP_THR 0.05f
#define LIST_CAP 8192

// fp32 -> bf16 hi (truncate) + bf16 lo (truncate of exact residual).
// a = hi + lo + eps, |eps| <= 2^-16 |a|; dot error std ~ 2^-16*sqrt(D) << GAP_THR.
__device__ __forceinline__ void cvt8(const f32x4& x, const f32x4& y,
                                     short8& hi, short8& lo) {
  float v[8] = {x[0], x[1], x[2], x[3], y[0], y[1], y[2], y[3]};
#pragma unroll
  for (int j = 0; j < 8; ++j) {
    unsigned b = __float_as_uint(v[j]);
    hi[j] = (short)(b >> 16);
    float l = v[j] - __uint_as_float(b & 0xffff0000u);
    lo[j] = (short)(__float_as_uint(l) >> 16);
  }
}

// Pre-convert eg [64 x 4096] fp32 -> bf16 hi/lo MFMA fragments, BKC=64 chunks.
// Unit u = ((c*2+p)*8 + s)*64 + l, s = j*4 + g: expert n=(s&3)*16+(l&15),
// k = c*64 + (s>>2)*32 + (l>>4)*8. 16B per unit = one lane-fragment.
// Also zeroes the fix-list counter.
__global__ __launch_bounds__(256)
void moe_precvt_kernel(const float* __restrict__ eg, short* __restrict__ egb,
                       int* __restrict__ cnt) {
  if (blockIdx.x == 0 && threadIdx.x == 0) *cnt = 0;
  int u = blockIdx.x * 256 + threadIdx.x;     // 65536 units
  int l = u & 63, s = (u >> 6) & 7, p = (u >> 9) & 1, c = u >> 10;
  int n = (s & 3) * 16 + (l & 15);
  int k = c * BKC + (s >> 2) * 32 + (l >> 4) * 8;
  const float* src = eg + (size_t)n * D_DIM + k;
  f32x4 x = *(const f32x4*)src;
  f32x4 y = *(const f32x4*)(src + 4);
  short8 hi, lo;
  cvt8(x, y, hi, lo);
  *(short8*)&egb[(size_t)u * 8] = (p == 0) ? hi : lo;
}

// Fused GEMM + top-2, barrier-free main loop. Block: 16 tokens x 64 experts,
// 4 waves (wave g = 16-expert group). B read directly from L2-resident egb
// (1 MB, no LDS staging, no syncthreads in the hot loop). A-rows shared by
// the 4 waves via L1/L2. Register double-buffer prefetches chunk c+1.
__global__ __launch_bounds__(256, 4)
void moe_main_kernel(const float* __restrict__ th, const short* __restrict__ egb,
                     const float* __restrict__ rl, const float* __restrict__ alpha_p,
                     float* __restrict__ out, int* __restrict__ cnt,
                     int* __restrict__ list) {
  __shared__ float gsc[16][68];                 // 4.3 KB score exchange
  const int tid  = threadIdx.x;
  const int lane = tid & 63;
  const int g    = __builtin_amdgcn_readfirstlane(tid >> 6);  // expert group
  const int m    = lane & 15, quad = lane >> 4;
  const int tb   = blockIdx.x;
  const int tok  = tb * 16 + m;
  const float* aptr = th + (size_t)tok * D_DIM + quad * 8;

  f32x4 acc = (f32x4){0.f, 0.f, 0.f, 0.f};

  f32x4  paA[4], paB[4];     // A: 2 ks-slices x 8 floats/lane
  short8 pbA[4], pbB[4];     // B: {hi j0, lo j0, hi j1, lo j1}

  auto loadA = [&](f32x4* pa, int c) {
    const float* ap = aptr + c * BKC;
    pa[0] = *(const f32x4*)ap;
    pa[1] = *(const f32x4*)(ap + 4);
    pa[2] = *(const f32x4*)(ap + 32);
    pa[3] = *(const f32x4*)(ap + 36);
  };
  auto loadB = [&](short8* pb, int c) {
    // short offset = c*8192 + p*4096 + j*2048 + g*512 + lane*8
    const short* bp = egb + (size_t)c * 8192 + g * 512 + lane * 8;
    pb[0] = *(const short8*)(bp);
    pb[1] = *(const short8*)(bp + 4096);
    pb[2] = *(const short8*)(bp + 2048);
    pb[3] = *(const short8*)(bp + 6144);
  };
  auto compute = [&](const f32x4* pa, const short8* pb) {
#pragma unroll
    for (int j = 0; j < 2; ++j) {
      short8 ahi, alo;
      cvt8(pa[2 * j], pa[2 * j + 1], ahi, alo);
      acc = __builtin_amdgcn_mfma_f32_16x16x32_bf16(ahi, pb[2 * j],     acc, 0, 0, 0);
      acc = __builtin_amdgcn_mfma_f32_16x16x32_bf16(ahi, pb[2 * j + 1], acc, 0, 0, 0);
      acc = __builtin_amdgcn_mfma_f32_16x16x32_bf16(alo, pb[2 * j],     acc, 0, 0, 0);
    }
  };

  loadA(paA, 0); loadB(pbA, 0);
#pragma unroll 1
  for (int c = 0; c < NCHUNK; c += 2) {
    loadA(paB, c + 1); loadB(pbB, c + 1);
    compute(paA, pbA);
    if (c + 2 < NCHUNK) { loadA(paA, c + 2); loadB(pbA, c + 2); }
    compute(paB, pbB);
  }

  // C/D layout: col(expert-within-group)=lane&15, row(token)=(lane>>4)*4+i
#pragma unroll
  for (int i = 0; i < 4; ++i)
    gsc[quad * 4 + i][g * 16 + m] = acc[i];
  __syncthreads();

  const float alpha = alpha_p[0];
#pragma unroll 1
  for (int tt = 0; tt < 4; ++tt) {
    int tl   = g * 4 + tt;
    int tokg = tb * 16 + tl;
    float gv = rl[(size_t)tokg * E_EXP + lane] + alpha * gsc[tl][lane];

    float v1 = gv; int i1 = lane;
#pragma unroll
    for (int off = 32; off > 0; off >>= 1) {
      float vo = __shfl_down(v1, off, 64);
      int   io = __shfl_down(i1, off, 64);
      if (vo > v1 || (vo == v1 && io < i1)) { v1 = vo; i1 = io; }
    }
    v1 = __shfl(v1, 0, 64); i1 = __shfl(i1, 0, 64);

    float g2 = (lane == i1) ? -3.4e38f : gv;
    float v2 = g2; int i2 = lane;
#pragma unroll
    for (int off = 32; off > 0; off >>= 1) {
      float vo = __shfl_down(v2, off, 64);
      int   io = __shfl_down(i2, off, 64);
      if (vo > v2 || (vo == v2 && io < i2)) { v2 = vo; i2 = io; }
    }
    v2 = __shfl(v2, 0, 64); i2 = __shfl(i2, 0, 64);

    // third-best value: needed to detect a near-tie at rank 2/3 (index risk)
    float g3 = (lane == i1 || lane == i2) ? -3.4e38f : gv;
    float v3 = g3;
#pragma unroll
    for (int off = 32; off > 0; off >>= 1)
      v3 = fmaxf(v3, __shfl_down(v3, off, 64));

    if (lane == 0) {
      float ew  = __expf(v2 - v1);
      float inv = 1.f / (1.f + ew);
      ((float4*)out)[tokg] = make_float4((float)i1, inv, (float)i2, ew * inv);
      if (v1 - v2 < GAP_THR || v2 - v3 < GAP_THR) {
        int idx = atomicAdd(cnt, 1);
        if (idx < LIST_CAP) list[idx] = tokg;
      }
    }
  }
}

// Exact fp32 recompute of flagged tokens (4 waves split k, lane=expert).
__global__ __launch_bounds__(256)
void moe_fix_kernel(const float* __restrict__ th, const float* __restrict__ eg,
                    const float* __restrict__ rl, const float* __restrict__ alpha_p,
                    float* __restrict__ out, const int* __restrict__ cnt,
                    const int* __restrict__ list) {
  __shared__ float lds_p[4][64];
  const int wave = threadIdx.x >> 6, lane = threadIdx.x & 63;
  const float alpha = alpha_p[0];
  int count = *cnt;
  if (count > LIST_CAP) count = LIST_CAP;

  for (int i = blockIdx.x; i < count; i += gridDim.x) {
    int t = list[i];
    const float* tr = th + (size_t)t * D_DIM + wave * 1024;
    const float* er = eg + (size_t)lane * D_DIM + wave * 1024;
    float d = 0.f;
    for (int k = 0; k < 1024; k += 4) {
      float4 a = *(const float4*)(tr + k);
      float4 b = *(const float4*)(er + k);
      d = fmaf(a.x, b.x, d); d = fmaf(a.y, b.y, d);
      d = fmaf(a.z, b.z, d); d = fmaf(a.w, b.w, d);
    }
    lds_p[wave][lane] = d;
    __syncthreads();
    if (wave == 0) {
      float dot = lds_p[0][lane] + lds_p[1][lane] + lds_p[2][lane] + lds_p[3][lane];
      float g = rl[(size_t)t * E_EXP + lane] + alpha * dot;
      float v1 = g; int i1 = lane;
#pragma unroll
      for (int off = 32; off > 0; off >>= 1) {
        float vo = __shfl_down(v1, off, 64);
        int   io = __shfl_down(i1, off, 64);
        if (vo > v1 || (vo == v1 && io < i1)) { v1 = vo; i1 = io; }
      }
      v1 = __shfl(v1, 0, 64); i1 = __shfl(i1, 0, 64);
      float g2 = (lane == i1) ? -3.4e38f : g;
      float v2 = g2; int i2 = lane;
#pragma unroll
      for (int off = 32; off > 0; off >>= 1) {
        float vo = __shfl_down(v2, off, 64);
        int   io = __shfl_down(i2, off, 64);
        if (vo > v2 || (vo == v2 && io < i2)) { v2 = vo; i2 = io; }
      }
      if (lane == 0) {
        float ew  = __expf(v2 - v1);
        float inv = 1.f / (1.f + ew);
        ((float4*)out)[t] = make_float4((float)i1, inv, (float)i2, ew * inv);
      }
    }
    __syncthreads();
  }
}

extern "C" void kernel_launch(void* const* d_in, const int* in_sizes, int n_in,
                              void* d_out, int out_size, void* d_ws, size_t ws_size,
                              hipStream_t stream) {
  const float* th      = (const float*)d_in[0];  // [T, D]
  const float* rl      = (const float*)d_in[1];  // [T, E]
  const float* eg      = (const float*)d_in[2];  // [E, D]
  const float* alpha_p = (const float*)d_in[3];  // scalar
  float* out = (float*)d_out;                    // [T, 2, 2]

  short* egb = (short*)d_ws;                     // 1 MB bf16 hi/lo fragments
  int* cnt   = (int*)((char*)d_ws + (1 << 20));
  int* list  = cnt + 64;

  moe_precvt_kernel<<<256, 256, 0, stream>>>(eg, egb, cnt);
  moe_main_kernel<<<T_TOK / 16, 256, 0, stream>>>(th, egb, rl, alpha_p, out, cnt, list);
  moe_fix_kernel<<<256, 256, 0, stream>>>(th, eg, rl, alpha_p, out, cnt, list);
}